// Round 2
// baseline (1512.741 us; speedup 1.0000x reference)
//
#include <hip/hip_runtime.h>
#include <hip/hip_bf16.h>

#define NB 256
#define NS 200
#define NPOS (NB*NS)
#define NW 8
#define EV_D 64
#define ITEM_D 256
#define HID 256
#define SKU_D 128
#define URL_D 128
#define LN_EPS 1e-5f

// Block-wide sum over 256 threads (4 waves). All threads must call (branches
// around calls are block-uniform in this kernel). Returns the sum to all threads.
__device__ __forceinline__ float block_sum(float v, float* red) {
    #pragma unroll
    for (int o = 32; o > 0; o >>= 1) v += __shfl_down(v, o, 64);
    const int lane = threadIdx.x & 63;
    const int w = threadIdx.x >> 6;
    __syncthreads();                 // protect red from previous call's readers
    if (lane == 0) red[w] = v;
    __syncthreads();
    return red[0] + red[1] + red[2] + red[3];
}

// LN for a D-length vector held one element per thread (threads t<D hold val).
// Returns normalized value for t<D, 0 otherwise.
__device__ __forceinline__ float block_ln(float val, int D, int t, float* red) {
    float v = (t < D) ? val : 0.f;
    float s = block_sum(v, red);
    float mu = s / (float)D;
    float d = (t < D) ? (v - mu) : 0.f;
    float s2 = block_sum(d * d, red);
    return d * rsqrtf(s2 / (float)D + LN_EPS);
}

extern "C" __global__ __launch_bounds__(256)
void encoder_kernel(const int* __restrict__ event_type,
                    const int* __restrict__ sku_id,
                    const int* __restrict__ url_id,
                    const int* __restrict__ cat_id,
                    const int* __restrict__ price_id,
                    const int* __restrict__ word_id,
                    const float* __restrict__ event_emb,
                    const float* __restrict__ word_emb,
                    const float* __restrict__ sku_emb,
                    const float* __restrict__ sku_proj_W,
                    const float* __restrict__ sku_proj_b,
                    const float* __restrict__ cat_emb,
                    const float* __restrict__ price_emb,
                    const float* __restrict__ fc1_W,
                    const float* __restrict__ fc1_b,
                    const float* __restrict__ url_emb,
                    const float* __restrict__ url_proj_W,
                    const float* __restrict__ url_proj_b,
                    float* __restrict__ out)
{
    __shared__ __align__(16) float x[1024];    // concat [se, ce, pe, we]
    __shared__ __align__(16) float tmp[128];   // ln'd 128-d embedding for proj input
    __shared__ float red[4];

    const int pos = blockIdx.x;
    const int t = threadIdx.x;
    const int e = event_type[pos];

    float* out_pos = out + (size_t)pos * 320;

    // mask output (tuple element 1), concatenated after user_emb
    if (t == 0) out[(size_t)NPOS * 320 + pos] = (e == 0) ? 1.0f : 0.0f;

    // ev = ln(event_emb[e]) -> out[0:64]
    {
        float v = (t < EV_D) ? event_emb[e * EV_D + t] : 0.f;
        float r = block_ln(v, EV_D, t, red);
        if (t < EV_D) out_pos[t] = r;
    }

    const bool sku_b   = (e >= 2) && (e <= 4);
    const bool url_b   = (e == 5);
    const bool query_b = (e == 6);

    float agg = 0.f;   // this thread's dim (t in [0,256)) of the 256-d agg

    // word layer (needed by sku and query branches): ln(mean_w word_emb[wid])
    if (sku_b || query_b) {
        const int* wid = word_id + (size_t)pos * NW;
        float acc = 0.f;
        #pragma unroll
        for (int w = 0; w < NW; ++w) {
            acc += word_emb[(size_t)wid[w] * ITEM_D + t];
        }
        acc *= (1.0f / NW);
        float we = block_ln(acc, ITEM_D, t, red);
        if (query_b) {
            agg = we;
        } else {
            x[768 + t] = we;
        }
    }

    if (sku_b) {
        // se128 = ln(sku_emb[sid])
        {
            float v = (t < SKU_D) ? sku_emb[(size_t)sku_id[pos] * SKU_D + t] : 0.f;
            float r = block_ln(v, SKU_D, t, red);
            __syncthreads();
            if (t < SKU_D) tmp[t] = r;
            __syncthreads();
        }
        // se = relu(ln(se128 @ sku_proj_W + b))
        {
            float h = sku_proj_b[t];
            const float4* t4 = (const float4*)tmp;
            #pragma unroll 8
            for (int d4 = 0; d4 < SKU_D / 4; ++d4) {
                float4 xv = t4[d4];
                const float* wp = sku_proj_W + d4 * 4 * HID + t;
                h = fmaf(xv.x, wp[0],       h);
                h = fmaf(xv.y, wp[HID],     h);
                h = fmaf(xv.z, wp[2 * HID], h);
                h = fmaf(xv.w, wp[3 * HID], h);
            }
            float se = block_ln(h, HID, t, red);
            x[t] = fmaxf(se, 0.f);
        }
        // ce = ln(cat_emb[cid])
        {
            float v = cat_emb[(size_t)cat_id[pos] * HID + t];
            x[256 + t] = block_ln(v, HID, t, red);
        }
        // pe = ln(price_emb[pid])
        {
            float v = price_emb[(size_t)price_id[pos] * HID + t];
            x[512 + t] = block_ln(v, HID, t, red);
        }
        __syncthreads();
        // item = relu(x @ fc1_W + b)
        {
            float acc = fc1_b[t];
            const float4* x4 = (const float4*)x;
            #pragma unroll 8
            for (int d4 = 0; d4 < 1024 / 4; ++d4) {
                float4 xv = x4[d4];
                const float* wp = fc1_W + d4 * 4 * HID + t;
                acc = fmaf(xv.x, wp[0],       acc);
                acc = fmaf(xv.y, wp[HID],     acc);
                acc = fmaf(xv.z, wp[2 * HID], acc);
                acc = fmaf(xv.w, wp[3 * HID], acc);
            }
            agg = fmaxf(acc, 0.f);
        }
    } else if (url_b) {
        // ue128 = ln(url_emb[uid])
        {
            float v = (t < URL_D) ? url_emb[(size_t)url_id[pos] * URL_D + t] : 0.f;
            float r = block_ln(v, URL_D, t, red);
            __syncthreads();
            if (t < URL_D) tmp[t] = r;
            __syncthreads();
        }
        // ue = relu(ln(ue128 @ url_proj_W + b))
        {
            float h = url_proj_b[t];
            const float4* t4 = (const float4*)tmp;
            #pragma unroll 8
            for (int d4 = 0; d4 < URL_D / 4; ++d4) {
                float4 xv = t4[d4];
                const float* wp = url_proj_W + d4 * 4 * HID + t;
                h = fmaf(xv.x, wp[0],       h);
                h = fmaf(xv.y, wp[HID],     h);
                h = fmaf(xv.z, wp[2 * HID], h);
                h = fmaf(xv.w, wp[3 * HID], h);
            }
            float ue = block_ln(h, HID, t, red);
            agg = fmaxf(ue, 0.f);
        }
    }
    // pad (e==0) and e==1: agg stays 0

    out_pos[64 + t] = agg;
}

extern "C" void kernel_launch(void* const* d_in, const int* in_sizes, int n_in,
                              void* d_out, int out_size, void* d_ws, size_t ws_size,
                              hipStream_t stream) {
    (void)in_sizes; (void)n_in; (void)out_size; (void)d_ws; (void)ws_size;
    const int*   event_type = (const int*)d_in[0];
    const int*   sku_id     = (const int*)d_in[1];
    const int*   url_id     = (const int*)d_in[2];
    const int*   cat_id     = (const int*)d_in[3];
    const int*   price_id   = (const int*)d_in[4];
    const int*   word_id    = (const int*)d_in[5];
    const float* event_emb  = (const float*)d_in[6];
    const float* word_emb   = (const float*)d_in[7];
    const float* sku_emb    = (const float*)d_in[8];
    const float* sku_proj_W = (const float*)d_in[9];
    const float* sku_proj_b = (const float*)d_in[10];
    const float* cat_emb    = (const float*)d_in[11];
    const float* price_emb  = (const float*)d_in[12];
    const float* fc1_W      = (const float*)d_in[13];
    const float* fc1_b      = (const float*)d_in[14];
    const float* url_emb    = (const float*)d_in[15];
    const float* url_proj_W = (const float*)d_in[16];
    const float* url_proj_b = (const float*)d_in[17];
    float* out = (float*)d_out;

    hipLaunchKernelGGL(encoder_kernel, dim3(NPOS), dim3(256), 0, stream,
                       event_type, sku_id, url_id, cat_id, price_id, word_id,
                       event_emb, word_emb, sku_emb, sku_proj_W, sku_proj_b,
                       cat_emb, price_emb, fc1_W, fc1_b,
                       url_emb, url_proj_W, url_proj_b, out);
}